// Round 5
// baseline (191.837 us; speedup 1.0000x reference)
//
#include <hip/hip_runtime.h>
#include <hip/hip_bf16.h>

typedef __attribute__((ext_vector_type(8))) short bf16x8;
typedef __attribute__((ext_vector_type(4))) float f32x4;

#define B_ 8
#define S_ 1024
#define R_ 16384
#define H_ 128
#define D_ 256     // input dim = 2H
#define F_ 384     // inter dim

__device__ __forceinline__ unsigned short f2bf(float x) {
    unsigned int u = __float_as_uint(x);
    u += 0x7FFF + ((u >> 16) & 1);   // round-to-nearest-even
    return (unsigned short)(u >> 16);
}

__device__ __forceinline__ unsigned pack2bf(float a, float b) {
    float2 t; t.x = a; t.y = b;
    __hip_bfloat162 h = __float22bfloat162_rn(t);   // v_cvt_pk_bf16_f32
    return *reinterpret_cast<unsigned*>(&h);
}

// One fused prep kernel: span fp32->bf16, W1 transpose+cvt, W2 transpose+cvt.
__global__ __launch_bounds__(256) void k_prep(const float* __restrict__ span,
                                              const float* __restrict__ W1,
                                              const float* __restrict__ W2,
                                              unsigned short* __restrict__ spanbf,
                                              unsigned short* __restrict__ W1T,
                                              unsigned short* __restrict__ W2T) {
    const int bid = blockIdx.x;
    const int t = threadIdx.x;
    if (bid < 1024) {
        int i = bid * 256 + t;
        float4 v = reinterpret_cast<const float4*>(span)[i];
        ushort4 o;
        o.x = f2bf(v.x); o.y = f2bf(v.y); o.z = f2bf(v.z); o.w = f2bf(v.w);
        reinterpret_cast<ushort4*>(spanbf)[i] = o;
    } else if (bid < 1408) {
        int i = (bid - 1024) * 256 + t;       // W1T[f][d] = W1[d][f]
        int d = i & 255, f = i >> 8;
        W1T[i] = f2bf(W1[d * F_ + f]);
    } else {
        int i = (bid - 1408) * 256 + t;       // W2T[o][f] = W2[f][o]
        int o = i / F_, f = i - o * F_;
        W2T[i] = f2bf(W2[f * H_ + o]);
    }
}

// PERSISTENT kernel: 256 blocks (1 per CU), 512 threads (8 waves), each block
// processes 8 tiles of 64 rows. W1 (96 VGPR) + W2 (48 VGPR) fragments live in
// registers for the whole kernel -> the MFMA loops contain ZERO global loads.
// LDS 112 KiB: sA double-buffered 2 x [64][256] bf16 (32 KiB each, XOR-swizzled
// byte^=((m&7)<<4)) + sH [64][384] bf16 (48 KiB, same swizzle).
// Per tile: [barA] L1(ds_read+MFMA) -> issue gathers(t+1) -> epi1(relu->sH) ->
// ds_write gathers -> [barB] L2(ds_read+MFMA) -> direct float4 stores.
// Layer 1: wave w owns f in [w*48,+48). Layer 2: wave w owns o in [w*16,+16).
// Swapped mfma operands (W as A-operand): lane holds 4 consecutive f / o.
__global__ __launch_bounds__(512, 2) void k_main(
    const unsigned short* __restrict__ spanbf,
    const int* __restrict__ rel_ids,
    const unsigned short* __restrict__ W1T,
    const float* __restrict__ b1,
    const unsigned short* __restrict__ W2T,
    const float* __restrict__ b2,
    float* __restrict__ out)
{
    extern __shared__ char smem[];
    char* sH = smem + 65536;                  // 48 KiB

    const int tid = threadIdx.x;
    const int bid = blockIdx.x;               // 0..255
    const int b   = bid >> 5;                 // batch (32 blocks per batch, 512 rows each)
    const int row_blk = bid << 9;             // first global row of this block

    const int w  = tid >> 6;   // wave 0..7
    const int l  = tid & 63;
    const int lr = l & 15;
    const int lg = l >> 4;

    // ---------------- persistent weight fragments (registers) ----------------
    bf16x8 W1f[3][8];                         // [ft][kt], f-slice w*48..+48
    {
        const unsigned short* w1p = W1T + (unsigned)(w * 48 + lr) * 256 + lg * 8;
        #pragma unroll
        for (int ft = 0; ft < 3; ++ft)
            #pragma unroll
            for (int kt = 0; kt < 8; ++kt)
                W1f[ft][kt] = *reinterpret_cast<const bf16x8*>(w1p + ft * 4096 + kt * 32);
    }
    bf16x8 W2f[12];                           // o-slice w*16..+16
    {
        const unsigned short* w2p = W2T + (unsigned)(w * 16 + lr) * 384 + lg * 8;
        #pragma unroll
        for (int kt = 0; kt < 12; ++kt)
            W2f[kt] = *reinterpret_cast<const bf16x8*>(w2p + kt * 32);
    }

    // bias fragments (persistent)
    const int fb0 = w * 48 + lg * 4;
    const float4 bias1_0 = *reinterpret_cast<const float4*>(b1 + fb0);
    const float4 bias1_1 = *reinterpret_cast<const float4*>(b1 + fb0 + 16);
    const float4 bias1_2 = *reinterpret_cast<const float4*>(b1 + fb0 + 32);
    const int ob = w * 16 + lg * 4;
    const float4 bias2 = *reinterpret_cast<const float4*>(b2 + ob);

    // ---------------- gather addressing ----------------
    const int gm = tid >> 3;                  // row in tile (0..63)
    const int ge = tid & 7;                   // eighth of the 512-B row
    const int gswz = (gm & 7) << 4;
    const int gbase = gm * 512 + ge * 64;
    const long spanbase = ((long)(b << 10)) << 7;   // batch base in spanbf elems

    // stage tile 0 into sA[0]
    {
        const int2 ids = reinterpret_cast<const int2*>(rel_ids)[row_blk + gm];
        const int idx = (ge < 4) ? ids.x : ids.y;
        const uint4* src = reinterpret_cast<const uint4*>(
            spanbf + spanbase + ((long)idx << 7) + ((ge & 3) << 5));
        #pragma unroll
        for (int j = 0; j < 4; ++j) {
            uint4 v = src[j];
            *reinterpret_cast<uint4*>(smem + ((gbase + j * 16) ^ gswz)) = v;
        }
    }

    // L1 ds_read offset bases (swizzle decomposed: kt bit0 collides with swz bit6)
    int aOff[4][2];
    #pragma unroll
    for (int mt = 0; mt < 4; ++mt) {
        const int m = mt * 16 + lr;
        const int swz = (m & 7) << 4;
        const int e0 = m * 512 + ((lg << 4) ^ (swz & 0x30)) + (swz & 0x40);
        aOff[mt][0] = e0;
        aOff[mt][1] = e0 ^ 64;
    }

    // ================= persistent tile loop =================
    #pragma unroll 1
    for (int t = 0; t < 8; ++t) {
        char* sAcur = smem + ((t & 1) << 15);
        char* sAnxt = smem + (((t & 1) ^ 1) << 15);

        __syncthreads();                      // barA: sA(cur) staged, sH free

        // prefetch next tile's ids early (consumed ~L1-length later)
        int2 ids2;
        if (t < 7)
            ids2 = reinterpret_cast<const int2*>(rel_ids)[row_blk + (t + 1) * 64 + gm];

        // ---------------- layer 1: pure ds_read + MFMA ----------------
        f32x4 acc[3][4];
        #pragma unroll
        for (int ft = 0; ft < 3; ++ft)
            #pragma unroll
            for (int mt = 0; mt < 4; ++mt) acc[ft][mt] = {0.f, 0.f, 0.f, 0.f};

        #pragma unroll
        for (int kt = 0; kt < 8; ++kt) {
            bf16x8 Af[4];
            #pragma unroll
            for (int mt = 0; mt < 4; ++mt)
                Af[mt] = *reinterpret_cast<const bf16x8*>(
                    sAcur + aOff[mt][kt & 1] + (kt >> 1) * 128);
            #pragma unroll
            for (int ft = 0; ft < 3; ++ft)
                #pragma unroll
                for (int mt = 0; mt < 4; ++mt)
                    acc[ft][mt] = __builtin_amdgcn_mfma_f32_16x16x32_bf16(
                        W1f[ft][kt], Af[mt], acc[ft][mt], 0, 0, 0);
        }

        // issue next tile's gather loads (latency hides under epilogue 1)
        uint4 g0, g1, g2, g3;
        if (t < 7) {
            const int idx = (ge < 4) ? ids2.x : ids2.y;
            const uint4* src = reinterpret_cast<const uint4*>(
                spanbf + spanbase + ((long)idx << 7) + ((ge & 3) << 5));
            g0 = src[0]; g1 = src[1]; g2 = src[2]; g3 = src[3];
        }

        // ---------------- epilogue 1: bias + relu -> sH ----------------
        #pragma unroll
        for (int ft = 0; ft < 3; ++ft) {
            const int fb = w * 48 + ft * 16 + lg * 4;
            const float4 bias = (ft == 0) ? bias1_0 : (ft == 1) ? bias1_1 : bias1_2;
            #pragma unroll
            for (int mt = 0; mt < 4; ++mt) {
                float v0 = fmaxf(acc[ft][mt][0] + bias.x, 0.0f);
                float v1 = fmaxf(acc[ft][mt][1] + bias.y, 0.0f);
                float v2 = fmaxf(acc[ft][mt][2] + bias.z, 0.0f);
                float v3 = fmaxf(acc[ft][mt][3] + bias.w, 0.0f);
                uint2 p;
                p.x = pack2bf(v0, v1);
                p.y = pack2bf(v2, v3);
                const int m = mt * 16 + lr;
                *reinterpret_cast<uint2*>(
                    sH + ((m * 768 + fb * 2) ^ ((m & 7) << 4))) = p;
            }
        }

        // stage next tile into the other sA buffer
        if (t < 7) {
            *reinterpret_cast<uint4*>(sAnxt + ((gbase +  0) ^ gswz)) = g0;
            *reinterpret_cast<uint4*>(sAnxt + ((gbase + 16) ^ gswz)) = g1;
            *reinterpret_cast<uint4*>(sAnxt + ((gbase + 32) ^ gswz)) = g2;
            *reinterpret_cast<uint4*>(sAnxt + ((gbase + 48) ^ gswz)) = g3;
        }

        __syncthreads();                      // barB: sH ready, sA(nxt) staged

        // ---------------- layer 2: pure ds_read + MFMA ----------------
        f32x4 acc2[4];
        #pragma unroll
        for (int mt = 0; mt < 4; ++mt) acc2[mt] = {0.f, 0.f, 0.f, 0.f};

        #pragma unroll
        for (int kt = 0; kt < 12; ++kt) {
            #pragma unroll
            for (int mt = 0; mt < 4; ++mt) {
                const int m = mt * 16 + lr;
                bf16x8 Hf = *reinterpret_cast<const bf16x8*>(
                    sH + ((m * 768 + kt * 64 + lg * 16) ^ ((m & 7) << 4)));
                acc2[mt] = __builtin_amdgcn_mfma_f32_16x16x32_bf16(
                    W2f[kt], Hf, acc2[mt], 0, 0, 0);
            }
        }

        // epilogue 2: bias + direct float4 stores
        float* outp = out + ((long)(row_blk + t * 64)) * 128;
        #pragma unroll
        for (int mt = 0; mt < 4; ++mt) {
            const int m = mt * 16 + lr;
            float4 v;
            v.x = acc2[mt][0] + bias2.x;
            v.y = acc2[mt][1] + bias2.y;
            v.z = acc2[mt][2] + bias2.z;
            v.w = acc2[mt][3] + bias2.w;
            *reinterpret_cast<float4*>(outp + m * 128 + ob) = v;
        }
    }
}

extern "C" void kernel_launch(void* const* d_in, const int* in_sizes, int n_in,
                              void* d_out, int out_size, void* d_ws, size_t ws_size,
                              hipStream_t stream) {
    const float* span = (const float*)d_in[0];
    const int*   rel  = (const int*)d_in[1];
    const float* W1   = (const float*)d_in[2];
    const float* b1   = (const float*)d_in[3];
    const float* W2   = (const float*)d_in[4];
    const float* b2   = (const float*)d_in[5];
    float* out = (float*)d_out;

    unsigned short* spanbf = (unsigned short*)d_ws;        // 2 MiB
    unsigned short* W1T = spanbf + B_ * S_ * H_;           // 192 KiB
    unsigned short* W2T = W1T + D_ * F_;                   // 96 KiB

    k_prep<<<1600, 256, 0, stream>>>(span, W1, W2, spanbf, W1T, W2T);
    k_main<<<256, 512, 114688, stream>>>(spanbf, rel, W1T, b1, W2T, b2, out);
}

// Round 6
// 146.167 us; speedup vs baseline: 1.3125x; 1.3125x over previous
//
#include <hip/hip_runtime.h>
#include <hip/hip_bf16.h>

typedef __attribute__((ext_vector_type(8))) short bf16x8;
typedef __attribute__((ext_vector_type(4))) float f32x4;

#define B_ 8
#define S_ 1024
#define R_ 16384
#define H_ 128
#define D_ 256     // input dim = 2H
#define F_ 384     // inter dim

__device__ __forceinline__ unsigned short f2bf(float x) {
    unsigned int u = __float_as_uint(x);
    u += 0x7FFF + ((u >> 16) & 1);   // round-to-nearest-even
    return (unsigned short)(u >> 16);
}

__device__ __forceinline__ unsigned pack2bf(float a, float b) {
    float2 t; t.x = a; t.y = b;
    __hip_bfloat162 h = __float22bfloat162_rn(t);   // v_cvt_pk_bf16_f32
    return *reinterpret_cast<unsigned*>(&h);
}

// One fused prep kernel: span fp32->bf16, W1 transpose+cvt, W2 transpose+cvt.
__global__ __launch_bounds__(256) void k_prep(const float* __restrict__ span,
                                              const float* __restrict__ W1,
                                              const float* __restrict__ W2,
                                              unsigned short* __restrict__ spanbf,
                                              unsigned short* __restrict__ W1T,
                                              unsigned short* __restrict__ W2T) {
    const int bid = blockIdx.x;
    const int t = threadIdx.x;
    if (bid < 1024) {
        int i = bid * 256 + t;
        float4 v = reinterpret_cast<const float4*>(span)[i];
        ushort4 o;
        o.x = f2bf(v.x); o.y = f2bf(v.y); o.z = f2bf(v.z); o.w = f2bf(v.w);
        reinterpret_cast<ushort4*>(spanbf)[i] = o;
    } else if (bid < 1408) {
        int i = (bid - 1024) * 256 + t;       // W1T[f][d] = W1[d][f]
        int d = i & 255, f = i >> 8;
        W1T[i] = f2bf(W1[d * F_ + f]);
    } else {
        int i = (bid - 1408) * 256 + t;       // W2T[o][f] = W2[f][o]
        int o = i / F_, f = i - o * F_;
        W2T[i] = f2bf(W2[f * H_ + o]);
    }
}

// 64 rows/block, 8 waves (512 threads), ONE barrier per block.
// Layer 1 reads A-fragments DIRECTLY from global (L2-resident spanbf): for the
// swapped-operand MFMA, lane (lr,lg) needs span_row[m][kt*32+lg*8 ..+8] -- a
// contiguous 16 B global load. No sA staging, no stage barrier.
// LDS: sH only, [64][384] bf16 (48 KiB), XOR-swizzled byte^=((m&7)<<4).
// Layer 1: wave w owns f in [w*48,+48), W1 frags loaded in-loop from L2.
// Layer 2: wave w owns o in [w*16,+16), W2 frags preloaded (48 VGPR).
// Swapped mfma operands (W as A-operand): lane holds 4 consecutive f / o.
__global__ __launch_bounds__(512, 4) void k_main(
    const unsigned short* __restrict__ spanbf,
    const int* __restrict__ rel_ids,
    const unsigned short* __restrict__ W1T,
    const float* __restrict__ b1,
    const unsigned short* __restrict__ W2T,
    const float* __restrict__ b2,
    float* __restrict__ out)
{
    extern __shared__ char smem[];
    char* sH = smem;                          // [64][384] bf16, stride 768 B, swizzled

    const int tid = threadIdx.x;
    const int blk = blockIdx.x;               // 0..2047
    const int m0  = blk << 6;                 // first global row
    const int b   = m0 >> 14;                 // batch
    const int r0  = m0 & 16383;

    const int w  = tid >> 6;   // wave 0..7
    const int l  = tid & 63;
    const int lr = l & 15;
    const int lg = l >> 4;

    // ---------------- per-mt head/tail span-row pointers ----------------
    const unsigned short* ap[4][2];           // [mt][head/tail], + lg*8 folded in
    {
        const long spanbase = ((long)b << 17);            // b*1024*128 elements
        const int* idp = rel_ids + (((long)b << 14) + r0) * 2;
        #pragma unroll
        for (int mt = 0; mt < 4; ++mt) {
            const int m = mt * 16 + lr;
            const int2 ids = reinterpret_cast<const int2*>(idp)[m];
            ap[mt][0] = spanbf + spanbase + ((long)ids.x << 7) + lg * 8;
            ap[mt][1] = spanbf + spanbase + ((long)ids.y << 7) + lg * 8;
        }
    }

    // bias fragments
    const int fb0 = w * 48 + lg * 4;
    const float4 bias1_0 = *reinterpret_cast<const float4*>(b1 + fb0);
    const float4 bias1_1 = *reinterpret_cast<const float4*>(b1 + fb0 + 16);
    const float4 bias1_2 = *reinterpret_cast<const float4*>(b1 + fb0 + 32);
    const int ob = w * 16 + lg * 4;
    const float4 bias2 = *reinterpret_cast<const float4*>(b2 + ob);

    // ---------------- layer 1: global A + global W1 + MFMA ----------------
    const unsigned short* w1p = W1T + (unsigned)(w * 48 + lr) * 256 + lg * 8;

    f32x4 acc[3][4];
    #pragma unroll
    for (int ft = 0; ft < 3; ++ft)
        #pragma unroll
        for (int mt = 0; mt < 4; ++mt) acc[ft][mt] = {0.f, 0.f, 0.f, 0.f};

    #pragma unroll
    for (int kt = 0; kt < 8; ++kt) {
        bf16x8 Af[4];
        #pragma unroll
        for (int mt = 0; mt < 4; ++mt)
            Af[mt] = *reinterpret_cast<const bf16x8*>(ap[mt][kt >> 2] + (kt & 3) * 32);
        #pragma unroll
        for (int ft = 0; ft < 3; ++ft) {
            bf16x8 Wf = *reinterpret_cast<const bf16x8*>(w1p + ft * 4096 + kt * 32);
            #pragma unroll
            for (int mt = 0; mt < 4; ++mt)
                acc[ft][mt] = __builtin_amdgcn_mfma_f32_16x16x32_bf16(
                    Wf, Af[mt], acc[ft][mt], 0, 0, 0);
        }
    }

    // ---------------- epilogue 1: bias + relu -> sH (packed b64) ----------
    #pragma unroll
    for (int ft = 0; ft < 3; ++ft) {
        const int fb = w * 48 + ft * 16 + lg * 4;
        const float4 bias = (ft == 0) ? bias1_0 : (ft == 1) ? bias1_1 : bias1_2;
        #pragma unroll
        for (int mt = 0; mt < 4; ++mt) {
            float v0 = fmaxf(acc[ft][mt][0] + bias.x, 0.0f);
            float v1 = fmaxf(acc[ft][mt][1] + bias.y, 0.0f);
            float v2 = fmaxf(acc[ft][mt][2] + bias.z, 0.0f);
            float v3 = fmaxf(acc[ft][mt][3] + bias.w, 0.0f);
            uint2 p;
            p.x = pack2bf(v0, v1);
            p.y = pack2bf(v2, v3);
            const int m = mt * 16 + lr;
            *reinterpret_cast<uint2*>(
                sH + ((m * 768 + fb * 2) ^ ((m & 7) << 4))) = p;
        }
    }

    // preload W2 fragments (48 VGPR) — issued before the barrier, consumed after
    bf16x8 W2f[12];
    {
        const unsigned short* w2p = W2T + (unsigned)(w * 16 + lr) * 384 + lg * 8;
        #pragma unroll
        for (int kt = 0; kt < 12; ++kt)
            W2f[kt] = *reinterpret_cast<const bf16x8*>(w2p + kt * 32);
    }

    __syncthreads();                          // the ONLY barrier: sH ready

    // ---------------- layer 2: ds_read + MFMA (W2 in regs) ----------------
    // decomposed swizzle bases: kt bit0 collides with swz bit6
    int hOff[4][2];
    #pragma unroll
    for (int mt = 0; mt < 4; ++mt) {
        const int m = mt * 16 + lr;
        const int swz = (m & 7) << 4;
        const int e0 = m * 768 + ((lg << 4) ^ (swz & 0x30)) + (swz & 0x40);
        hOff[mt][0] = e0;
        hOff[mt][1] = e0 ^ 64;
    }

    f32x4 acc2[4];
    #pragma unroll
    for (int mt = 0; mt < 4; ++mt) acc2[mt] = {0.f, 0.f, 0.f, 0.f};

    #pragma unroll
    for (int kt = 0; kt < 12; ++kt) {
        #pragma unroll
        for (int mt = 0; mt < 4; ++mt) {
            bf16x8 Hf = *reinterpret_cast<const bf16x8*>(
                sH + hOff[mt][kt & 1] + (kt >> 1) * 128);
            acc2[mt] = __builtin_amdgcn_mfma_f32_16x16x32_bf16(
                W2f[kt], Hf, acc2[mt], 0, 0, 0);
        }
    }

    // ---------------- epilogue 2: bias + direct float4 stores ----------------
    float* outp = out + (long)m0 * 128;
    #pragma unroll
    for (int mt = 0; mt < 4; ++mt) {
        const int m = mt * 16 + lr;
        float4 v;
        v.x = acc2[mt][0] + bias2.x;
        v.y = acc2[mt][1] + bias2.y;
        v.z = acc2[mt][2] + bias2.z;
        v.w = acc2[mt][3] + bias2.w;
        *reinterpret_cast<float4*>(outp + m * 128 + ob) = v;
    }
}

extern "C" void kernel_launch(void* const* d_in, const int* in_sizes, int n_in,
                              void* d_out, int out_size, void* d_ws, size_t ws_size,
                              hipStream_t stream) {
    const float* span = (const float*)d_in[0];
    const int*   rel  = (const int*)d_in[1];
    const float* W1   = (const float*)d_in[2];
    const float* b1   = (const float*)d_in[3];
    const float* W2   = (const float*)d_in[4];
    const float* b2   = (const float*)d_in[5];
    float* out = (float*)d_out;

    unsigned short* spanbf = (unsigned short*)d_ws;        // 2 MiB
    unsigned short* W1T = spanbf + B_ * S_ * H_;           // 192 KiB
    unsigned short* W2T = W1T + D_ * F_;                   // 96 KiB

    k_prep<<<1600, 256, 0, stream>>>(span, W1, W2, spanbf, W1T, W2T);
    k_main<<<(B_ * R_) / 64, 512, 49152, stream>>>(spanbf, rel, W1T, b1, W2T, b2, out);
}